// Round 9
// baseline (85.423 us; speedup 1.0000x reference)
//
#include <hip/hip_runtime.h>

typedef unsigned short u16;
typedef unsigned int   u32;
typedef u16   u16x8 __attribute__((ext_vector_type(8)));
typedef float f32x4 __attribute__((ext_vector_type(4)));
typedef __bf16 bf16x8 __attribute__((ext_vector_type(8)));
typedef u32   u32x2 __attribute__((ext_vector_type(2)));
typedef u32   u32x4 __attribute__((ext_vector_type(4)));

#define LOG2E 1.44269504088896f
#define RTHR  5.545177444479562f   // 8*ln2: defer-rescale threshold

__device__ __forceinline__ u16 f2bf(float x){
  __bf16 h = (__bf16)x;
  return __builtin_bit_cast(u16, h);
}
__device__ __forceinline__ f32x4 mfma16x16x32(u16x8 a, u16x8 b, f32x4 c){
  return __builtin_amdgcn_mfma_f32_16x16x32_bf16(
      __builtin_bit_cast(bf16x8, a), __builtin_bit_cast(bf16x8, b), c, 0, 0, 0);
}
__device__ __forceinline__ void gld16(const void* g, void* l){
  __builtin_amdgcn_global_load_lds(
      (const __attribute__((address_space(1))) u32*)g,
      (__attribute__((address_space(3))) u32*)l, 16, 0, 0);
}

// ===================== pre-pass: f32 KV -> swizzled bf16 tile image ==========
__global__ __launch_bounds__(256, 4)
void prepass(const float* __restrict__ KV, const int* __restrict__ MASK,
             u16* __restrict__ IMG, float* __restrict__ BIAS)
{
  const int tid = threadIdx.x;
  const int bid = blockIdx.x;        // ((b*16+h)*32 + kt)
  const int kt = bid & 31;
  const int h  = (bid >> 5) & 15;
  const int b  = bid >> 9;
  const int kb = kt*64;
  const size_t kv_b = (size_t)b*(2048u*2048u);
  u16* tile = IMG + (size_t)bid * 9216;

  {
    const int skey = tid >> 2, scp = tid & 3;
    const float* kp = KV + kv_b + (size_t)(kb + skey)*2048 + h*64 + 16*scp;
    f32x4 f0 = *(const f32x4*)(kp);
    f32x4 f1 = *(const f32x4*)(kp + 4);
    f32x4 f2 = *(const f32x4*)(kp + 8);
    f32x4 f3 = *(const f32x4*)(kp + 12);
    u16x8 c0, c1;
    #pragma unroll
    for (int e = 0; e < 4; ++e){
      c0[e] = f2bf(f0[e]); c0[e+4] = f2bf(f1[e]);
      c1[e] = f2bf(f2[e]); c1[e+4] = f2bf(f3[e]);
    }
    const int sw = (skey >> 3) & 7;
    *(u16x8*)&tile[skey*72 + (((2*scp    ) ^ sw) << 3)] = c0;
    *(u16x8*)&tile[skey*72 + (((2*scp + 1) ^ sw) << 3)] = c1;
  }
  {
    const int sdb = tid & 7, ssp = tid >> 3;
    const float* vp = KV + kv_b + (size_t)(kb + 2*ssp)*2048 + 1024 + h*64 + 8*sdb;
    f32x4 r0a = *(const f32x4*)(vp);
    f32x4 r0b = *(const f32x4*)(vp + 4);
    f32x4 r1a = *(const f32x4*)(vp + 2048);
    f32x4 r1b = *(const f32x4*)(vp + 2048 + 4);
    u32* vimg = (u32*)(tile + 4608);
    const int swc = ((ssp >> 2) ^ sdb) << 2;
    #pragma unroll
    for (int j = 0; j < 4; ++j){
      const int d0 = 8*sdb + j;
      const int d1 = d0 + 4;
      vimg[d0*36 + swc + (ssp & 3)] = (u32)f2bf(r0a[j]) | ((u32)f2bf(r1a[j]) << 16);
      vimg[d1*36 + swc + (ssp & 3)] = (u32)f2bf(r0b[j]) | ((u32)f2bf(r1b[j]) << 16);
    }
  }
  if (h == 0 && tid < 64){
    const int s = kb + tid;
    BIAS[b*2048 + s] = MASK[b*2048 + s] ? 0.f : -10000.f;
  }
}

// ===================== main: pipelined MFMA flash attention ==================
// Triple-buffered LDS; DMA staging (PRE=1) or reg staging (PRE=0 fallback).
// Per iter t: [stage-write(PRE=0)] barrier; DMA(t+2); QK(t+1) ; softmax(t)+PV(t).
template<int PRE>
__global__ __launch_bounds__(256, 2)
void attn_main(const float* __restrict__ Q, const float* __restrict__ KV,
               const int* __restrict__ MASK, const u16* __restrict__ IMG,
               const float* __restrict__ BIAS, float* __restrict__ OUT)
{
  __shared__ __align__(16) u16 KVbuf[3][9216];   // [K 4608 u16 | V 4608 u16] x3
  __shared__ __align__(16) u32 Pw[4][32*36];     // per-wave P[q][s] bf16 packed

  const int tid  = threadIdx.x;
  const int w    = tid >> 6;
  const int lane = tid & 63;
  const int lg   = lane >> 4;
  const int ln   = lane & 15;

  const int bid0 = blockIdx.x;
  const int bid  = (bid0 & 7)*64 + (bid0 >> 3);   // XCD swizzle
  const int qt  = bid & 15;
  const int h   = (bid >> 4) & 15;
  const int b   = bid >> 8;

  const int qbase = qt*128 + w*32;
  const size_t q_b  = (size_t)b * (2048u*1024u);
  const size_t kv_b = (size_t)b * (2048u*2048u);

  // ---- Q fragments (f32 -> bf16, pre-scaled by 1/8) ----
  u16x8 Qf[2][2];
  #pragma unroll
  for (int G = 0; G < 2; ++G){
    const int qrow = qbase + 16*G + ln;
    const float* qp = Q + q_b + (size_t)qrow*1024 + h*64 + 8*lg;
    #pragma unroll
    for (int kc = 0; kc < 2; ++kc){
      f32x4 a = *(const f32x4*)(qp + 32*kc);
      f32x4 c = *(const f32x4*)(qp + 32*kc + 4);
      u16x8 v;
      #pragma unroll
      for (int e = 0; e < 4; ++e){
        v[e]     = f2bf(a[e] * 0.125f);
        v[e + 4] = f2bf(c[e] * 0.125f);
      }
      Qf[G][kc] = v;
    }
  }

  f32x4 Oacc[2][4];
  #pragma unroll
  for (int G = 0; G < 2; ++G)
    #pragma unroll
    for (int dt = 0; dt < 4; ++dt)
      Oacc[G][dt] = f32x4{0.f, 0.f, 0.f, 0.f};
  float mrun[2] = { -3.0e38f, -3.0e38f };
  float lrun[2] = { 0.f, 0.f };     // per-lane PARTIAL sums (reduced in epilogue)

  // staging constants
  const char* img0 = (const char*)IMG + (size_t)((b*16 + h)*32) * 18432;
  const int  so   = tid*16;
  const bool tail = (tid < 128);    // wave-uniform (waves 0,1)
  const int skey = tid >> 2, scp = tid & 3;
  const int sdb  = tid & 7,  ssp = tid >> 3;
  const int swk  = (skey >> 3) & 7;
  const int swc  = ((ssp >> 2) ^ sdb) << 2;
  const float* kp0 = KV + kv_b + (size_t)skey*2048 + h*64 + 16*scp;
  const float* vp0 = KV + kv_b + (size_t)(2*ssp)*2048 + 1024 + h*64 + 8*sdb;
  f32x4 kf0, kf1, kf2, kf3, va, vb2, vc, vd;   // PRE=0 staging regs

  u16* bcur  = &KVbuf[0][0];
  u16* bnxt  = &KVbuf[1][0];
  u16* bfree = &KVbuf[2][0];

#define STAGE_ISSUE(T, DST) do{                                               \
    if constexpr (PRE){                                                       \
      const char* g_ = img0 + (size_t)(T)*18432;                              \
      char* l_ = (char*)(DST);                                                \
      gld16(g_+so,        l_+so);                                             \
      gld16(g_+so+4096,   l_+so+4096);                                        \
      gld16(g_+so+8192,   l_+so+8192);                                        \
      gld16(g_+so+12288,  l_+so+12288);                                       \
      if (tail) gld16(g_+16384+so, l_+16384+so);                              \
    } else {                                                                  \
      const float* kp_ = kp0 + (size_t)(T)*64*2048;                           \
      kf0=*(const f32x4*)(kp_);   kf1=*(const f32x4*)(kp_+4);                 \
      kf2=*(const f32x4*)(kp_+8); kf3=*(const f32x4*)(kp_+12);                \
      const float* vp_ = vp0 + (size_t)(T)*64*2048;                           \
      va=*(const f32x4*)(vp_);      vb2=*(const f32x4*)(vp_+4);               \
      vc=*(const f32x4*)(vp_+2048); vd =*(const f32x4*)(vp_+2048+4);          \
    }                                                                         \
  }while(0)

#define STAGE_WRITE(DST) do{                                                  \
    u16x8 c0_, c1_;                                                           \
    _Pragma("unroll") for (int e_=0; e_<4; ++e_){                             \
      c0_[e_]=f2bf(kf0[e_]); c0_[e_+4]=f2bf(kf1[e_]);                         \
      c1_[e_]=f2bf(kf2[e_]); c1_[e_+4]=f2bf(kf3[e_]); }                       \
    *(u16x8*)&(DST)[skey*72 + (((2*scp  )^swk)<<3)] = c0_;                    \
    *(u16x8*)&(DST)[skey*72 + (((2*scp+1)^swk)<<3)] = c1_;                    \
    u32* vimg_ = (u32*)((DST)+4608);                                          \
    _Pragma("unroll") for (int j_=0; j_<4; ++j_){                             \
      const int d0_=8*sdb+j_, d1_=d0_+4;                                      \
      vimg_[d0_*36 + swc + (ssp&3)] = (u32)f2bf(va[j_])  | ((u32)f2bf(vc[j_])<<16); \
      vimg_[d1_*36 + swc + (ssp&3)] = (u32)f2bf(vb2[j_]) | ((u32)f2bf(vd[j_])<<16); \
    }                                                                         \
  }while(0)

#define QK_TILE(SN, KB) do{                                                   \
    _Pragma("unroll") for (int G_=0; G_<2; ++G_)                              \
      _Pragma("unroll") for (int ct_=0; ct_<4; ++ct_)                         \
        SN[G_][ct_] = f32x4{0.f,0.f,0.f,0.f};                                 \
    _Pragma("unroll") for (int ct_=0; ct_<4; ++ct_){                          \
      const int row_ = 16*ct_ + ln;                                           \
      const int sw_  = (row_ >> 3) & 7;                                       \
      _Pragma("unroll") for (int kc_=0; kc_<2; ++kc_){                        \
        u16x8 kfr_ = *(const u16x8*)&(KB)[row_*72 + (((lg + 4*kc_) ^ sw_) << 3)]; \
        SN[0][ct_] = mfma16x16x32(kfr_, Qf[0][kc_], SN[0][ct_]);              \
        SN[1][ct_] = mfma16x16x32(kfr_, Qf[1][kc_], SN[1][ct_]);              \
      } }                                                                     \
  }while(0)

#define SOFTMAX_PV(SC, T, VB) do{                                             \
    _Pragma("unroll") for (int ct_=0; ct_<4; ++ct_){                          \
      f32x4 bv_;                                                              \
      if constexpr (PRE){                                                     \
        bv_ = *(const f32x4*)(BIAS + b*2048 + (T)*64 + 16*ct_ + 4*lg);        \
      } else {                                                                \
        const int4 mv_ = *(const int4*)(MASK + b*2048 + (T)*64 + 16*ct_ + 4*lg); \
        bv_[0]=mv_.x?0.f:-10000.f; bv_[1]=mv_.y?0.f:-10000.f;                 \
        bv_[2]=mv_.z?0.f:-10000.f; bv_[3]=mv_.w?0.f:-10000.f;                 \
      }                                                                       \
      _Pragma("unroll") for (int r_=0; r_<4; ++r_){                           \
        SC[0][ct_][r_] += bv_[r_]; SC[1][ct_][r_] += bv_[r_]; }               \
    }                                                                         \
    _Pragma("unroll") for (int G_=0; G_<2; ++G_){                             \
      float m0_ = fmaxf(fmaxf(SC[G_][0][0],SC[G_][0][1]),fmaxf(SC[G_][0][2],SC[G_][0][3])); \
      float m1_ = fmaxf(fmaxf(SC[G_][1][0],SC[G_][1][1]),fmaxf(SC[G_][1][2],SC[G_][1][3])); \
      float m2_ = fmaxf(fmaxf(SC[G_][2][0],SC[G_][2][1]),fmaxf(SC[G_][2][2],SC[G_][2][3])); \
      float m3_ = fmaxf(fmaxf(SC[G_][3][0],SC[G_][3][1]),fmaxf(SC[G_][3][2],SC[G_][3][3])); \
      float mx_ = fmaxf(fmaxf(m0_,m1_), fmaxf(m2_,m3_));                      \
      mx_ = fmaxf(mx_, __shfl_xor(mx_, 16, 64));                              \
      mx_ = fmaxf(mx_, __shfl_xor(mx_, 32, 64));                              \
      if (__any(mx_ > mrun[G_] + RTHR)){                                      \
        const float mn_ = fmaxf(mrun[G_], mx_);                               \
        const float corr_ = __builtin_amdgcn_exp2f((mrun[G_] - mn_) * LOG2E); \
        mrun[G_] = mn_; lrun[G_] *= corr_;                                    \
        _Pragma("unroll") for (int dt_=0; dt_<4; ++dt_)                       \
          _Pragma("unroll") for (int r_=0; r_<4; ++r_)                        \
            Oacc[G_][dt_][r_] *= corr_;                                       \
      }                                                                       \
      const float mc_ = mrun[G_] * LOG2E;                                     \
      float ps_ = 0.f;                                                        \
      _Pragma("unroll") for (int ct_=0; ct_<4; ++ct_){                        \
        _Pragma("unroll") for (int r_=0; r_<4; ++r_){                         \
          const float p_ = __builtin_amdgcn_exp2f(__builtin_fmaf(SC[G_][ct_][r_], LOG2E, -mc_)); \
          SC[G_][ct_][r_] = p_; ps_ += p_; } }                                \
      lrun[G_] += ps_;                                                        \
      _Pragma("unroll") for (int ct_=0; ct_<4; ++ct_){                        \
        u32x2 pw_;                                                            \
        pw_[0] = (u32)f2bf(SC[G_][ct_][0]) | ((u32)f2bf(SC[G_][ct_][1]) << 16); \
        pw_[1] = (u32)f2bf(SC[G_][ct_][2]) | ((u32)f2bf(SC[G_][ct_][3]) << 16); \
        *(u32x2*)&Pw[w][(16*G_ + ln)*36 + 8*ct_ + 2*lg] = pw_;                \
      }                                                                       \
    }                                                                         \
    asm volatile("" ::: "memory");                                            \
    u16x8 Pf_[2][2];                                                          \
    _Pragma("unroll") for (int G_=0; G_<2; ++G_)                              \
      _Pragma("unroll") for (int sc_=0; sc_<2; ++sc_){                        \
        u32x4 pr_ = *(const u32x4*)&Pw[w][(16*G_ + ln)*36 + 4*lg + 16*sc_];   \
        Pf_[G_][sc_] = __builtin_bit_cast(u16x8, pr_); }                      \
    _Pragma("unroll") for (int dt_=0; dt_<4; ++dt_){                          \
      const int row_ = 16*dt_ + ln;                                           \
      const int sw_  = (row_ >> 3) & 7;                                       \
      _Pragma("unroll") for (int sc_=0; sc_<2; ++sc_){                        \
        u16x8 vf_ = *(const u16x8*)&(VB)[row_*72 + (((lg + 4*sc_) ^ sw_) << 3)]; \
        Oacc[0][dt_] = mfma16x16x32(vf_, Pf_[0][sc_], Oacc[0][dt_]);          \
        Oacc[1][dt_] = mfma16x16x32(vf_, Pf_[1][sc_], Oacc[1][dt_]);          \
      } }                                                                     \
  }while(0)

#define ATTN_ITER(T, SC, SN) do{                                              \
    if constexpr (!PRE) { STAGE_WRITE(bnxt); }                                \
    __syncthreads();                                                          \
    if ((T) + 2 <= 31) STAGE_ISSUE((T)+2, bfree);                             \
    QK_TILE(SN, bnxt);                                                        \
    SOFTMAX_PV(SC, (T), bcur + 4608);                                         \
    { u16* t_ = bcur; bcur = bnxt; bnxt = bfree; bfree = t_; }                \
  }while(0)

  // ---- prologue: tile0 resident, tile1 in flight, S(0) computed ----
  STAGE_ISSUE(0, bcur);
  if constexpr (!PRE) { STAGE_WRITE(bcur); }
  __syncthreads();
  STAGE_ISSUE(1, bnxt);

  f32x4 Sa[2][4], Sb[2][4];
  QK_TILE(Sa, bcur);

  for (int tp = 0; tp < 15; ++tp){
    ATTN_ITER(2*tp,     Sa, Sb);
    ATTN_ITER(2*tp + 1, Sb, Sa);
  }
  ATTN_ITER(30, Sa, Sb);
  // tail t=31: no QK, no staging
  SOFTMAX_PV(Sb, 31, bcur + 4608);

  // ---- epilogue: reduce partial l across lane groups, normalize, store ----
  #pragma unroll
  for (int G = 0; G < 2; ++G){
    float l_ = lrun[G];
    l_ += __shfl_xor(l_, 16, 64);
    l_ += __shfl_xor(l_, 32, 64);
    const float inv = 1.f / l_;
    const int qrow = qbase + 16*G + ln;
    float* op = OUT + q_b + (size_t)qrow*1024 + h*64;
    #pragma unroll
    for (int dt = 0; dt < 4; ++dt){
      f32x4 ov;
      ov[0] = Oacc[G][dt][0] * inv;
      ov[1] = Oacc[G][dt][1] * inv;
      ov[2] = Oacc[G][dt][2] * inv;
      ov[3] = Oacc[G][dt][3] * inv;
      *(f32x4*)(op + 16*dt + 4*lg) = ov;
    }
  }
#undef STAGE_ISSUE
#undef STAGE_WRITE
#undef QK_TILE
#undef SOFTMAX_PV
#undef ATTN_ITER
}

extern "C" void kernel_launch(void* const* d_in, const int* in_sizes, int n_in,
                              void* d_out, int out_size, void* d_ws, size_t ws_size,
                              hipStream_t stream)
{
  const float* Q  = nullptr;
  const float* KV = nullptr;
  const int*   M  = nullptr;
  for (int i = 0; i < n_in; ++i){
    if      (in_sizes[i] == 4194304) Q  = (const float*)d_in[i];
    else if (in_sizes[i] == 8388608) KV = (const float*)d_in[i];
    else if (in_sizes[i] == 4096)    M  = (const int*)d_in[i];
  }
  if (!Q)  Q  = (const float*)d_in[0];
  if (!KV) KV = (const float*)d_in[1];
  if (!M)  M  = (const int*)d_in[2];
  float* O = (float*)d_out;

  const size_t NEED = 16384ull + 1024ull*18432ull;   // bias + KV image
  if (ws_size >= NEED){
    float* bias = (float*)d_ws;
    u16*   img  = (u16*)((char*)d_ws + 16384);
    prepass<<<dim3(1024), dim3(256), 0, stream>>>(KV, M, img, bias);
    attn_main<1><<<dim3(512), dim3(256), 0, stream>>>(Q, KV, M, img, bias, O);
  } else {
    attn_main<0><<<dim3(512), dim3(256), 0, stream>>>(Q, KV, M, nullptr, nullptr, O);
  }
}